// Round 1
// baseline (448.229 us; speedup 1.0000x reference)
//
#include <hip/hip_runtime.h>

#define IN_W 224
#define IMG_CH (224*224)        // 50176
#define IMG_SZ (3*IMG_CH)       // 150528
#define P1 37
#define P1SZ (P1*P1)            // 1369

// One block per image. Fuses conv1(3x3,s2)+maxpool3+relu -> LDS[3,37,37],
// conv2(3x3,s2)+maxpool3+relu -> [36], linear 36->6 -> d_ws.
__global__ __launch_bounds__(256) void branch_kernel(
    const float* __restrict__ nodes, const float* __restrict__ depths,
    const float* __restrict__ c1w, const float* __restrict__ c1b,
    const float* __restrict__ c2w, const float* __restrict__ c2b,
    const float* __restrict__ lw,  const float* __restrict__ lb,
    const float* __restrict__ d1w, const float* __restrict__ d1b,
    const float* __restrict__ d2w, const float* __restrict__ d2b,
    const float* __restrict__ dlw, const float* __restrict__ dlb,
    float* __restrict__ feat_ws, float* __restrict__ dfeat_ws)
{
    __shared__ float pool1[3 * P1SZ];   // 4107 floats = 16.4 KB
    __shared__ float pool2[36];

    const int img = blockIdx.x;
    const float* in;
    const float *w1, *b1, *w2, *b2, *lwp, *lbp;
    float* outp;
    if (img < 320) {
        in = nodes + (size_t)img * IMG_SZ;
        w1 = c1w; b1 = c1b; w2 = c2w; b2 = c2b; lwp = lw; lbp = lb;
        outp = feat_ws + img * 6;
    } else {
        const int im = img - 320;
        in = depths + (size_t)im * IMG_SZ;
        w1 = d1w; b1 = d1b; w2 = d2w; b2 = d2b; lwp = dlw; lbp = dlb;
        outp = dfeat_ws + im * 6;
    }
    const int t = threadIdx.x;

    // Phase 1: each item = one pooled spatial site (py,px), all 3 out channels.
    for (int item = t; item < P1SZ; item += 256) {
        const int py = item / P1, px = item % P1;
        float acc[3][9];
        #pragma unroll
        for (int c = 0; c < 3; ++c) {
            const float bv = b1[c];
            #pragma unroll
            for (int q = 0; q < 9; ++q) acc[c][q] = bv;
        }
        const float* ib0 = in + (6 * py) * IN_W + 6 * px;
        #pragma unroll
        for (int ic = 0; ic < 3; ++ic) {
            const float* ib = ib0 + ic * IMG_CH;
            float p[7][7];
            #pragma unroll
            for (int u = 0; u < 7; ++u)
                #pragma unroll
                for (int v = 0; v < 7; ++v)
                    p[u][v] = ib[u * IN_W + v];
            #pragma unroll
            for (int c = 0; c < 3; ++c)
                #pragma unroll
                for (int ky = 0; ky < 3; ++ky)
                    #pragma unroll
                    for (int kx = 0; kx < 3; ++kx)
                        #pragma unroll
                        for (int u = 0; u < 3; ++u)
                            #pragma unroll
                            for (int v = 0; v < 3; ++v)
                                acc[c][ky*3+kx] = fmaf(p[2*ky+u][2*kx+v],
                                                       w1[c*27 + ic*9 + u*3 + v],
                                                       acc[c][ky*3+kx]);
        }
        #pragma unroll
        for (int c = 0; c < 3; ++c) {
            float m = acc[c][0];
            #pragma unroll
            for (int q = 1; q < 9; ++q) m = fmaxf(m, acc[c][q]);
            pool1[c * P1SZ + item] = fmaxf(m, 0.f);   // relu(maxpool(conv1))
        }
    }
    __syncthreads();

    // Phase 2: conv2 (3->1 ch, 3x3, s2) + maxpool3 + relu -> pool2[36]
    if (t < 36) {
        const int qy = t / 6, qx = t % 6;
        float acc[9];
        const float bv = b2[0];
        #pragma unroll
        for (int q = 0; q < 9; ++q) acc[q] = bv;
        #pragma unroll
        for (int ic = 0; ic < 3; ++ic) {
            float p[7][7];
            #pragma unroll
            for (int u = 0; u < 7; ++u)
                #pragma unroll
                for (int v = 0; v < 7; ++v)
                    p[u][v] = pool1[ic * P1SZ + (6*qy + u) * P1 + 6*qx + v];
            #pragma unroll
            for (int ky = 0; ky < 3; ++ky)
                #pragma unroll
                for (int kx = 0; kx < 3; ++kx)
                    #pragma unroll
                    for (int u = 0; u < 3; ++u)
                        #pragma unroll
                        for (int v = 0; v < 3; ++v)
                            acc[ky*3+kx] = fmaf(p[2*ky+u][2*kx+v],
                                                w2[ic*9 + u*3 + v],
                                                acc[ky*3+kx]);
        }
        float m = acc[0];
        #pragma unroll
        for (int q = 1; q < 9; ++q) m = fmaxf(m, acc[q]);
        pool2[t] = fmaxf(m, 0.f);
    }
    __syncthreads();

    // Phase 3: linear 36 -> 6
    if (t < 6) {
        float s = lbp[t];
        #pragma unroll
        for (int k = 0; k < 36; ++k) s = fmaf(pool2[k], lwp[t*36 + k], s);
        outp[t] = s;
    }
}

// One block per batch element: message passing + fc1/fc2/fc3.
__global__ __launch_bounds__(256) void head_kernel(
    const float* __restrict__ pos, const float* __restrict__ attmap,
    const float* __restrict__ fmp_w, const float* __restrict__ fmp_b,
    const float* __restrict__ lmp_w, const float* __restrict__ lmp_b,
    const float* __restrict__ fc1_w, const float* __restrict__ fc1_b,
    const float* __restrict__ fc2_w, const float* __restrict__ fc2_b,
    const float* __restrict__ fc3_w, const float* __restrict__ fc3_b,
    const float* __restrict__ feat_ws, const float* __restrict__ dfeat_ws,
    float* __restrict__ out)
{
    __shared__ float na[240];     // nodes_all [5][4][12]
    __shared__ float msg[240];
    __shared__ float lastb[240];
    __shared__ __align__(16) float x[360];
    __shared__ __align__(16) float h1[180];
    __shared__ float h2[60];
    const int b = blockIdx.x, t = threadIdx.x;

    if (t < 240) {
        const int k = t % 12, m = (t / 12) % 4, f = t / 48;
        na[t] = (k < 6) ? feat_ws[b*120 + f*24 + m*6 + k]
                        : pos[b*120 + f*24 + m*6 + (k - 6)];
    }
    __syncthreads();
    if (t < 240) {
        const int d = t % 12, base = (t / 12) * 12;
        float s1 = fmp_b[d], s2 = lmp_b[d];
        #pragma unroll
        for (int k = 0; k < 12; ++k) {
            const float v = na[base + k];
            s1 = fmaf(v, fmp_w[d*12 + k], s1);
            s2 = fmaf(v, lmp_w[d*12 + k], s2);
        }
        msg[t] = s1; lastb[t] = s2;
    }
    __syncthreads();
    if (t < 240) {
        const int d = t % 12, n = (t / 12) % 4, f = t / 48;
        float s = 0.f;
        #pragma unroll
        for (int m = 0; m < 4; ++m)
            s = fmaf(attmap[b*80 + f*16 + m*4 + n], msg[f*48 + m*12 + d], s);
        if (f > 0) s += lastb[(f-1)*48 + n*12 + d];
        x[(f*4 + n)*18 + d] = s;
    }
    if (t < 120) {
        const int j = t % 6, n = (t / 6) % 4, f = t / 24;
        x[(f*4 + n)*18 + 12 + j] = dfeat_ws[b*120 + f*24 + n*6 + j];
    }
    __syncthreads();
    if (t < 180) {
        const float4* wr = (const float4*)(fc1_w + t * 360);
        const float4* xs = (const float4*)x;
        float s = fc1_b[t];
        #pragma unroll 10
        for (int k = 0; k < 90; ++k) {
            const float4 w4 = wr[k]; const float4 x4 = xs[k];
            s = fmaf(w4.x, x4.x, s); s = fmaf(w4.y, x4.y, s);
            s = fmaf(w4.z, x4.z, s); s = fmaf(w4.w, x4.w, s);
        }
        h1[t] = fmaxf(s, 0.f);
    }
    __syncthreads();
    if (t < 60) {
        const float4* wr = (const float4*)(fc2_w + t * 180);
        const float4* hs = (const float4*)h1;
        float s = fc2_b[t];
        #pragma unroll
        for (int k = 0; k < 45; ++k) {
            const float4 w4 = wr[k]; const float4 x4 = hs[k];
            s = fmaf(w4.x, x4.x, s); s = fmaf(w4.y, x4.y, s);
            s = fmaf(w4.z, x4.z, s); s = fmaf(w4.w, x4.w, s);
        }
        h2[t] = fmaxf(s, 0.f);
    }
    __syncthreads();
    if (t < 6) {
        float s = fc3_b[t];
        #pragma unroll
        for (int k = 0; k < 60; ++k) s = fmaf(h2[k], fc3_w[t*60 + k], s);
        out[b*6 + t] = s;
    }
}

extern "C" void kernel_launch(void* const* d_in, const int* in_sizes, int n_in,
                              void* d_out, int out_size, void* d_ws, size_t ws_size,
                              hipStream_t stream) {
    const float* nodes  = (const float*)d_in[0];
    const float* pos    = (const float*)d_in[1];
    const float* attmap = (const float*)d_in[2];
    const float* depths = (const float*)d_in[3];
    const float* c1w = (const float*)d_in[4],  *c1b = (const float*)d_in[5];
    const float* c2w = (const float*)d_in[6],  *c2b = (const float*)d_in[7];
    const float* lw  = (const float*)d_in[8],  *lb  = (const float*)d_in[9];
    const float* d1w = (const float*)d_in[10], *d1b = (const float*)d_in[11];
    const float* d2w = (const float*)d_in[12], *d2b = (const float*)d_in[13];
    const float* dlw = (const float*)d_in[14], *dlb = (const float*)d_in[15];
    const float* fmpw = (const float*)d_in[16], *fmpb = (const float*)d_in[17];
    const float* lmpw = (const float*)d_in[18], *lmpb = (const float*)d_in[19];
    const float* fc1w = (const float*)d_in[20], *fc1b = (const float*)d_in[21];
    const float* fc2w = (const float*)d_in[22], *fc2b = (const float*)d_in[23];
    const float* fc3w = (const float*)d_in[24], *fc3b = (const float*)d_in[25];

    float* feat_ws  = (float*)d_ws;          // 320*6 = 1920 floats
    float* dfeat_ws = feat_ws + 1920;        // 1920 floats

    branch_kernel<<<640, 256, 0, stream>>>(
        nodes, depths, c1w, c1b, c2w, c2b, lw, lb,
        d1w, d1b, d2w, d2b, dlw, dlb, feat_ws, dfeat_ws);

    head_kernel<<<16, 256, 0, stream>>>(
        pos, attmap, fmpw, fmpb, lmpw, lmpb,
        fc1w, fc1b, fc2w, fc2b, fc3w, fc3b,
        feat_ws, dfeat_ws, (float*)d_out);
}